// Round 1
// baseline (382.886 us; speedup 1.0000x reference)
//
#include <hip/hip_runtime.h>
#include <hip/hip_bf16.h>
#include <cstdint>

using bf16 = __hip_bfloat16;
typedef short short8 __attribute__((ext_vector_type(8)));   // 8 bf16 = 4 VGPRs (MFMA A/B frag)
typedef float floatx4 __attribute__((ext_vector_type(4)));  // MFMA C/D frag

#define LOG2E 1.44269504088896340736f

// async global->LDS, 16B/lane. LDS dest must be wave-uniform base; HW adds lane*16.
__device__ __forceinline__ void async_load16(const bf16* g, bf16* l) {
    __builtin_amdgcn_global_load_lds(
        (const __attribute__((address_space(1))) uint32_t*)g,
        (__attribute__((address_space(3))) uint32_t*)l, 16, 0, 0);
}

// ---------------- fp32 -> bf16 bulk convert (x) ----------------
__global__ __launch_bounds__(256)
void cvt_bf16_kernel(const float* __restrict__ in, bf16* __restrict__ out) {
    const int i = (blockIdx.x * 256 + threadIdx.x) * 4;
    const float4 v = *(const float4*)(in + i);
    bf16 o[4] = {__float2bfloat16(v.x), __float2bfloat16(v.y),
                 __float2bfloat16(v.z), __float2bfloat16(v.w)};
    *(ushort4*)(out + i) = *(ushort4*)o;  // 8B store
}

// ------------- fp32 [R][C] -> bf16 [C][R] tiled transpose -------------
__global__ __launch_bounds__(256)
void transpose_cvt_kernel(const float* __restrict__ in, bf16* __restrict__ out,
                          int R, int C) {
    __shared__ float tile[32][33];
    const int tx = threadIdx.x & 31, ty = threadIdx.x >> 5;
    const int c0 = blockIdx.x * 32, r0 = blockIdx.y * 32;
    #pragma unroll
    for (int i = 0; i < 32; i += 8)
        tile[ty + i][tx] = in[(size_t)(r0 + ty + i) * C + c0 + tx];
    __syncthreads();
    #pragma unroll
    for (int i = 0; i < 32; i += 8)
        out[(size_t)(c0 + ty + i) * R + r0 + tx] = __float2bfloat16(tile[tx][ty + i]);
}

// ---------------- m97-pattern GEMM: C = A[M,K] @ Bt[N,K]^T + bias ----------------
// MODE 0: N=3072 qkv epilogue -> scatter Q(scaled)/K to [B,H,T,D], V to [B,H,D,T] bf16
// MODE 1: N=1024 out epilogue -> fp32 d_out
template <int MODE>
__global__ __launch_bounds__(256, 2)
void gemm_bt_kernel(const bf16* __restrict__ A, const bf16* __restrict__ Bt,
                    const float* __restrict__ bias, int K,
                    bf16* __restrict__ q_ws, bf16* __restrict__ k_ws,
                    bf16* __restrict__ vt_ws, float* __restrict__ out, int N) {
    __shared__ bf16 As[128 * 32];
    __shared__ bf16 Bs[128 * 32];
    const int tid = threadIdx.x;
    const int wave = tid >> 6, lane = tid & 63;
    const int ln = lane & 15, quad = lane >> 4;
    const int wm = wave & 1, wn = wave >> 1;           // 2x2 waves of 64x64
    const int m0 = blockIdx.y * 128, n0 = blockIdx.x * 128;

    floatx4 acc[4][4] = {};

    for (int k0 = 0; k0 < K; k0 += 32) {
        __syncthreads();  // all frag reads of previous tile done
        #pragma unroll
        for (int c = 0; c < 2; ++c) {
            const int e = (c * 256 + tid) * 8;          // linear elem in 128x32 tile
            async_load16(A + (size_t)(m0 + (e >> 5)) * K + k0 + (e & 31),
                         &As[(c * 256 + wave * 64) * 8]);
        }
        #pragma unroll
        for (int c = 0; c < 2; ++c) {
            const int e = (c * 256 + tid) * 8;
            async_load16(Bt + (size_t)(n0 + (e >> 5)) * K + k0 + (e & 31),
                         &Bs[(c * 256 + wave * 64) * 8]);
        }
        __syncthreads();  // drains vmcnt: tiles resident

        short8 af[4], bfr[4];
        #pragma unroll
        for (int i = 0; i < 4; ++i) {
            af[i]  = *(const short8*)&As[(wm * 64 + i * 16 + ln) * 32 + quad * 8];
            bfr[i] = *(const short8*)&Bs[(wn * 64 + i * 16 + ln) * 32 + quad * 8];
        }
        #pragma unroll
        for (int mi = 0; mi < 4; ++mi)
            #pragma unroll
            for (int ni = 0; ni < 4; ++ni)
                acc[mi][ni] = __builtin_amdgcn_mfma_f32_16x16x32_bf16(
                    af[mi], bfr[ni], acc[mi][ni], 0, 0, 0);
    }

    // epilogue; C/D layout: col=lane&15, row=quad*4+reg
    #pragma unroll
    for (int ni = 0; ni < 4; ++ni) {
        const int col = n0 + wn * 64 + ni * 16 + ln;
        const float bv = bias[col];
        if (MODE == 0) {
            const int which = col >> 10;        // 0=q 1=k 2=v (block-uniform)
            const int cc = col & 1023;
            const int h = cc >> 6, d = cc & 63;
            #pragma unroll
            for (int mi = 0; mi < 4; ++mi) {
                const int rowb = m0 + wm * 64 + mi * 16 + quad * 4;
                #pragma unroll
                for (int r = 0; r < 4; ++r) {
                    const int row = rowb + r;
                    const int bb = row >> 10, t = row & 1023;
                    const float v = acc[mi][ni][r] + bv;
                    if (which == 0)       // Q pre-scaled by 1/sqrt(D)
                        q_ws[((size_t)(bb * 16 + h) * 1024 + t) * 64 + d] =
                            __float2bfloat16(v * 0.125f);
                    else if (which == 1)
                        k_ws[((size_t)(bb * 16 + h) * 1024 + t) * 64 + d] =
                            __float2bfloat16(v);
                    else                  // V transposed: [B,H,D,T]
                        vt_ws[((size_t)(bb * 16 + h) * 64 + d) * 1024 + t] =
                            __float2bfloat16(v);
                }
            }
        } else {
            #pragma unroll
            for (int mi = 0; mi < 4; ++mi) {
                const int rowb = m0 + wm * 64 + mi * 16 + quad * 4;
                #pragma unroll
                for (int r = 0; r < 4; ++r)
                    out[(size_t)(rowb + r) * N + col] = acc[mi][ni][r] + bv;
            }
        }
    }
}

// ---------------- causal flash attention ----------------
// grid: x = q-tile of 64 rows (16), y = b*16+h (128). 4 waves, 16 q-rows each.
__global__ __launch_bounds__(256, 2)
void attn_kernel(const bf16* __restrict__ Q, const bf16* __restrict__ K,
                 const bf16* __restrict__ Vt, bf16* __restrict__ O) {
    constexpr int T = 1024, D = 64;
    __shared__ bf16 Qs[64 * 64];    // [qrow][d]
    __shared__ bf16 Ks[128 * 64];   // [krow][d]
    __shared__ bf16 Vts[64 * 128];  // [d][krow]
    __shared__ bf16 Ps[64 * 128];   // [qrow][krow] (C-layout -> A-layout round trip)

    const int q0 = blockIdx.x * 64;
    const int bh = blockIdx.y;
    const int tid = threadIdx.x;
    const int wave = tid >> 6, lane = tid & 63;
    const int ln = lane & 15, quad = lane >> 4;

    const bf16* Qg = Q + (size_t)bh * T * D + (size_t)q0 * D;
    const bf16* Kg = K + (size_t)bh * T * D;
    const bf16* Vg = Vt + (size_t)bh * D * T;

    // stage Q once (contiguous 4096 elems)
    #pragma unroll
    for (int c = 0; c < 2; ++c) {
        const int e = (c * 256 + tid) * 8;
        async_load16(Qg + e, &Qs[(c * 256 + wave * 64) * 8]);
    }

    floatx4 oacc[4] = {};           // [nj(d/16)] rows quad*4+r
    float rm[4], rl[4];
    #pragma unroll
    for (int r = 0; r < 4; ++r) { rm[r] = -1e30f; rl[r] = 0.f; }

    const int last = (q0 + 63) >> 7;
    for (int kt = 0; kt <= last; ++kt) {
        __syncthreads();            // previous iter's LDS readers done
        const bf16* Kt = Kg + (size_t)kt * 128 * D;   // contiguous 8192 elems
        #pragma unroll
        for (int c = 0; c < 4; ++c) {
            const int e = (c * 256 + tid) * 8;
            async_load16(Kt + e, &Ks[(c * 256 + wave * 64) * 8]);
        }
        const bf16* Vtt = Vg + kt * 128;              // rows d, stride T
        #pragma unroll
        for (int c = 0; c < 4; ++c) {
            const int e = (c * 256 + tid) * 8;        // linear in [64][128]
            async_load16(Vtt + (size_t)(e >> 7) * T + (e & 127),
                         &Vts[(c * 256 + wave * 64) * 8]);
        }
        __syncthreads();            // drain: K/V (and Q on iter 0) resident

        // S = Q @ K^T  (Q pre-scaled by 1/sqrt(D))
        floatx4 sacc[8] = {};
        #pragma unroll
        for (int ks = 0; ks < 2; ++ks) {
            const short8 af = *(const short8*)&Qs[(wave * 16 + ln) * 64 + ks * 32 + quad * 8];
            #pragma unroll
            for (int nj = 0; nj < 8; ++nj) {
                const short8 bfr = *(const short8*)&Ks[(nj * 16 + ln) * 64 + ks * 32 + quad * 8];
                sacc[nj] = __builtin_amdgcn_mfma_f32_16x16x32_bf16(af, bfr, sacc[nj], 0, 0, 0);
            }
        }

        if (kt == last) {           // causal mask on the diagonal tile only
            #pragma unroll
            for (int nj = 0; nj < 8; ++nj)
                #pragma unroll
                for (int r = 0; r < 4; ++r) {
                    const int qg = q0 + wave * 16 + quad * 4 + r;
                    const int kg = kt * 128 + nj * 16 + ln;
                    if (kg > qg) sacc[nj][r] = -1e30f;
                }
        }

        // online softmax; rows owned: quad*4+r, cols per lane: nj*16+ln
        #pragma unroll
        for (int r = 0; r < 4; ++r) {
            float mx = sacc[0][r];
            #pragma unroll
            for (int nj = 1; nj < 8; ++nj) mx = fmaxf(mx, sacc[nj][r]);
            mx = fmaxf(mx, __shfl_xor(mx, 1, 16));
            mx = fmaxf(mx, __shfl_xor(mx, 2, 16));
            mx = fmaxf(mx, __shfl_xor(mx, 4, 16));
            mx = fmaxf(mx, __shfl_xor(mx, 8, 16));
            const float mo = rm[r];
            const float mn = fmaxf(mo, mx);
            const float alpha = exp2f((mo - mn) * LOG2E);
            rm[r] = mn;
            rl[r] *= alpha;
            #pragma unroll
            for (int nj = 0; nj < 4; ++nj) oacc[nj][r] *= alpha;
            float rs = 0.f;
            #pragma unroll
            for (int nj = 0; nj < 8; ++nj) {
                const float p = exp2f((sacc[nj][r] - mn) * LOG2E);
                rs += p;
                Ps[(wave * 16 + quad * 4 + r) * 128 + nj * 16 + ln] = __float2bfloat16(p);
            }
            rl[r] += rs;            // lane-partial; reduced across 16 lanes at end
        }

        // O += P @ V  (each wave reads only its own 16 P rows -> no barrier)
        #pragma unroll
        for (int ks = 0; ks < 4; ++ks) {
            const short8 pf = *(const short8*)&Ps[(wave * 16 + ln) * 128 + ks * 32 + quad * 8];
            #pragma unroll
            for (int nj = 0; nj < 4; ++nj) {
                const short8 vf = *(const short8*)&Vts[(nj * 16 + ln) * 128 + ks * 32 + quad * 8];
                oacc[nj] = __builtin_amdgcn_mfma_f32_16x16x32_bf16(pf, vf, oacc[nj], 0, 0, 0);
            }
        }
    }

    // epilogue: normalize and write [B,T,H*D] bf16
    const int b = bh >> 4, h = bh & 15;
    #pragma unroll
    for (int r = 0; r < 4; ++r) {
        float l = rl[r];
        l += __shfl_xor(l, 1, 16);
        l += __shfl_xor(l, 2, 16);
        l += __shfl_xor(l, 4, 16);
        l += __shfl_xor(l, 8, 16);
        const float inv = 1.0f / l;
        const int t = q0 + wave * 16 + quad * 4 + r;
        const size_t rowb = ((size_t)b * 1024 + t) * 1024 + h * 64;
        #pragma unroll
        for (int nj = 0; nj < 4; ++nj)
            O[rowb + nj * 16 + ln] = __float2bfloat16(oacc[nj][r] * inv);
    }
}

extern "C" void kernel_launch(void* const* d_in, const int* in_sizes, int n_in,
                              void* d_out, int out_size, void* d_ws, size_t ws_size,
                              hipStream_t stream) {
    const float* x     = (const float*)d_in[0];   // [8,1024,1024]
    const float* W_qkv = (const float*)d_in[1];   // [1024,3072]
    const float* b_qkv = (const float*)d_in[2];   // [3072]
    const float* W_out = (const float*)d_in[3];   // [1024,1024]
    const float* b_out = (const float*)d_in[4];   // [1024]
    float* out = (float*)d_out;                   // [8,1024,1024] fp32

    char* ws = (char*)d_ws;
    const size_t MB = 1u << 20;
    bf16* x_bf   = (bf16*)(ws + 0);        // 16 MB  [8192,1024]
    bf16* wqkv_t = (bf16*)(ws + 16 * MB);  //  6 MB  [3072,1024]
    bf16* wout_t = (bf16*)(ws + 22 * MB);  //  2 MB  [1024,1024]
    bf16* q_ws   = (bf16*)(ws + 24 * MB);  // 16 MB  [B,H,T,D]
    bf16* k_ws   = (bf16*)(ws + 40 * MB);  // 16 MB  [B,H,T,D]
    bf16* vt_ws  = (bf16*)(ws + 56 * MB);  // 16 MB  [B,H,D,T]
    bf16* ao_ws  = (bf16*)(ws + 72 * MB);  // 16 MB  [8192,1024]

    cvt_bf16_kernel<<<8192, 256, 0, stream>>>(x, x_bf);
    transpose_cvt_kernel<<<dim3(96, 32), 256, 0, stream>>>(W_qkv, wqkv_t, 1024, 3072);
    transpose_cvt_kernel<<<dim3(32, 32), 256, 0, stream>>>(W_out, wout_t, 1024, 1024);

    gemm_bt_kernel<0><<<dim3(24, 64), 256, 0, stream>>>(
        x_bf, wqkv_t, b_qkv, 1024, q_ws, k_ws, vt_ws, nullptr, 3072);

    attn_kernel<<<dim3(16, 128), 256, 0, stream>>>(q_ws, k_ws, vt_ws, ao_ws);

    gemm_bt_kernel<1><<<dim3(8, 64), 256, 0, stream>>>(
        ao_ws, wout_t, b_out, 1024, nullptr, nullptr, nullptr, out, 1024);
}

// Round 2
// 286.194 us; speedup vs baseline: 1.3379x; 1.3379x over previous
//
#include <hip/hip_runtime.h>
#include <hip/hip_bf16.h>
#include <cstdint>

using bf16 = __hip_bfloat16;
typedef short short8 __attribute__((ext_vector_type(8)));   // 8 bf16 = 4 VGPRs (MFMA A/B frag)
typedef float floatx4 __attribute__((ext_vector_type(4)));  // MFMA C/D frag

// async global->LDS, 16B/lane. LDS dest must be wave-uniform base; HW adds lane*16.
__device__ __forceinline__ void async_load16(const bf16* g, bf16* l) {
    __builtin_amdgcn_global_load_lds(
        (const __attribute__((address_space(1))) uint32_t*)g,
        (__attribute__((address_space(3))) uint32_t*)l, 16, 0, 0);
}

__device__ __forceinline__ uint32_t pack2(float a, float b) {
    union { bf16 h[2]; uint32_t u; } p;
    p.h[0] = __float2bfloat16(a);
    p.h[1] = __float2bfloat16(b);
    return p.u;
}

// ---------------- fp32 -> bf16 bulk convert (x) ----------------
__global__ __launch_bounds__(256)
void cvt_bf16_kernel(const float* __restrict__ in, bf16* __restrict__ out) {
    const int i = (blockIdx.x * 256 + threadIdx.x) * 4;
    const float4 v = *(const float4*)(in + i);
    bf16 o[4] = {__float2bfloat16(v.x), __float2bfloat16(v.y),
                 __float2bfloat16(v.z), __float2bfloat16(v.w)};
    *(ushort4*)(out + i) = *(ushort4*)o;  // 8B store
}

// ------------- fp32 [R][C] -> bf16 [C][R] tiled transpose -------------
__global__ __launch_bounds__(256)
void transpose_cvt_kernel(const float* __restrict__ in, bf16* __restrict__ out,
                          int R, int C) {
    __shared__ float tile[32][33];
    const int tx = threadIdx.x & 31, ty = threadIdx.x >> 5;
    const int c0 = blockIdx.x * 32, r0 = blockIdx.y * 32;
    #pragma unroll
    for (int i = 0; i < 32; i += 8)
        tile[ty + i][tx] = in[(size_t)(r0 + ty + i) * C + c0 + tx];
    __syncthreads();
    #pragma unroll
    for (int i = 0; i < 32; i += 8)
        out[(size_t)(c0 + ty + i) * R + r0 + tx] = __float2bfloat16(tile[tx][ty + i]);
}

// ---------------- m97-pattern GEMM: C = A[M,K] @ Bt[N,K]^T + bias ----------------
// MODE 0: N=3072 qkv epilogue -> scatter Q(scaled, *log2e/8)/K to swizzled [B,H,T,D],
//         V to swizzled [B,H,D,T] bf16. Swizzle: 16B chunks XOR'd by row so that the
//         attention kernel's LDS-resident tiles give conflict-free ds_read_b128.
// MODE 1: N=1024 out epilogue -> fp32 d_out
template <int MODE>
__global__ __launch_bounds__(256, 2)
void gemm_bt_kernel(const bf16* __restrict__ A, const bf16* __restrict__ Bt,
                    const float* __restrict__ bias, int K,
                    bf16* __restrict__ q_ws, bf16* __restrict__ k_ws,
                    bf16* __restrict__ vt_ws, float* __restrict__ out, int N) {
    __shared__ bf16 As[128 * 32];
    __shared__ bf16 Bs[128 * 32];
    const int tid = threadIdx.x;
    const int wave = tid >> 6, lane = tid & 63;
    const int ln = lane & 15, quad = lane >> 4;
    const int wm = wave & 1, wn = wave >> 1;           // 2x2 waves of 64x64
    const int m0 = blockIdx.y * 128, n0 = blockIdx.x * 128;

    floatx4 acc[4][4] = {};

    for (int k0 = 0; k0 < K; k0 += 32) {
        __syncthreads();  // all frag reads of previous tile done
        #pragma unroll
        for (int c = 0; c < 2; ++c) {
            const int e = (c * 256 + tid) * 8;          // linear elem in 128x32 tile
            async_load16(A + (size_t)(m0 + (e >> 5)) * K + k0 + (e & 31),
                         &As[(c * 256 + wave * 64) * 8]);
        }
        #pragma unroll
        for (int c = 0; c < 2; ++c) {
            const int e = (c * 256 + tid) * 8;
            async_load16(Bt + (size_t)(n0 + (e >> 5)) * K + k0 + (e & 31),
                         &Bs[(c * 256 + wave * 64) * 8]);
        }
        __syncthreads();  // drains vmcnt: tiles resident

        short8 af[4], bfr[4];
        #pragma unroll
        for (int i = 0; i < 4; ++i) {
            af[i]  = *(const short8*)&As[(wm * 64 + i * 16 + ln) * 32 + quad * 8];
            bfr[i] = *(const short8*)&Bs[(wn * 64 + i * 16 + ln) * 32 + quad * 8];
        }
        #pragma unroll
        for (int mi = 0; mi < 4; ++mi)
            #pragma unroll
            for (int ni = 0; ni < 4; ++ni)
                acc[mi][ni] = __builtin_amdgcn_mfma_f32_16x16x32_bf16(
                    af[mi], bfr[ni], acc[mi][ni], 0, 0, 0);
    }

    // epilogue; C/D layout: col=lane&15, row=quad*4+reg
    #pragma unroll
    for (int ni = 0; ni < 4; ++ni) {
        const int col = n0 + wn * 64 + ni * 16 + ln;
        const float bv = bias[col];
        if (MODE == 0) {
            const int which = col >> 10;        // 0=q 1=k 2=v (block-uniform)
            const int cc = col & 1023;
            const int h = cc >> 6, d = cc & 63;
            #pragma unroll
            for (int mi = 0; mi < 4; ++mi) {
                const int rowb = m0 + wm * 64 + mi * 16 + quad * 4;
                if (which == 2) {
                    // V^T, packed 4 consecutive t (same swizzle chunk since t%8 in {0,4})
                    const int bb = rowb >> 10, t = rowb & 1023;
                    const int tl = t & 63;
                    const int tt = (t & ~63) + ((((tl >> 3) ^ (d & 7)) << 3) | (tl & 7));
                    uint2 w2 = { pack2(acc[mi][ni][0] + bv, acc[mi][ni][1] + bv),
                                 pack2(acc[mi][ni][2] + bv, acc[mi][ni][3] + bv) };
                    *(uint2*)&vt_ws[((size_t)(bb * 16 + h) * 64 + d) * 1024 + tt] = w2;
                } else {
                    bf16* dst = (which == 0) ? q_ws : k_ws;
                    #pragma unroll
                    for (int r = 0; r < 4; ++r) {
                        const int row = rowb + r;
                        const int bb = row >> 10, t = row & 1023;
                        float v = acc[mi][ni][r] + bv;
                        if (which == 0) v *= 0.1803368801111601f;  // (1/8)*log2(e)
                        const int dd = (((d >> 3) ^ (t & 7)) << 3) | (d & 7);
                        dst[((size_t)(bb * 16 + h) * 1024 + t) * 64 + dd] =
                            __float2bfloat16(v);
                    }
                }
            }
        } else {
            #pragma unroll
            for (int mi = 0; mi < 4; ++mi) {
                const int rowb = m0 + wm * 64 + mi * 16 + quad * 4;
                #pragma unroll
                for (int r = 0; r < 4; ++r)
                    out[(size_t)(rowb + r) * N + col] = acc[mi][ni][r] + bv;
            }
        }
    }
}

// ---------------- causal flash attention (S^T formulation) ----------------
// grid: x = q-tile of 128 rows (8), y = b*16+h (128). 4 waves, 32 q-cols each.
// S^T = K·Q^T via mfma(a=K-frag, b=Q-frag): C col = q = lane&15 -> softmax reduce
// needs only shfl_xor(16/32); lane owns P rows -> packed b64 P writes.
// O^T = V^T·P^T keeps all frag reads contiguous b128. All LDS tiles XOR-swizzled
// (chunk' = chunk ^ (row&7)) for conflict-free banks; global q/k/vt are pre-swizzled.
__global__ __launch_bounds__(256, 3)
void attn_kernel(const bf16* __restrict__ Q, const bf16* __restrict__ K,
                 const bf16* __restrict__ Vt, bf16* __restrict__ O) {
    constexpr int T = 1024;
    __shared__ bf16 Qs[128 * 64];   // [q_local][d]      16 KB
    __shared__ bf16 Ks[64 * 64];    // [k_local][d]       8 KB
    __shared__ bf16 Vts[64 * 64];   // [d][t_local]       8 KB
    __shared__ bf16 Ps[128 * 64];   // [q_local][k_local] 16 KB

    const int jt = blockIdx.x;
    const int q0 = jt * 128;
    const int bh = blockIdx.y;
    const int tid = threadIdx.x;
    const int wave = tid >> 6, lane = tid & 63;
    const int ln = lane & 15, quad = lane >> 4;

    const bf16* Qg = Q + (size_t)bh * T * 64 + (size_t)q0 * 64;
    const bf16* Kg = K + (size_t)bh * T * 64;
    const bf16* Vg = Vt + (size_t)bh * 64 * T;

    // stage Q (128x64) once
    #pragma unroll
    for (int c = 0; c < 4; ++c)
        async_load16(Qg + (size_t)(c * 256 + tid) * 8, &Qs[(c * 256 + wave * 64) * 8]);
    __syncthreads();  // drain

    // hoist Q B-frags for the whole k-loop: B[d][q], q = lane&15
    short8 bq[2][2];
    #pragma unroll
    for (int qj = 0; qj < 2; ++qj)
        #pragma unroll
        for (int ks = 0; ks < 2; ++ks) {
            const int row = wave * 32 + qj * 16 + ln;
            const int ch = (ks * 4 + quad) ^ (row & 7);
            bq[qj][ks] = *(const short8*)&Qs[row * 64 + ch * 8];
        }

    floatx4 oacc[4][2] = {};            // O^T frags [dt][qj]
    float rm[2] = {-1e30f, -1e30f}, rl[2] = {0.f, 0.f};
    const int qbw = q0 + wave * 32;     // wave's lowest q

    const int nkt = 2 * jt + 2;
    for (int kt = 0; kt < nkt; ++kt) {
        __syncthreads();                // prev iter's LDS readers done
        #pragma unroll
        for (int c = 0; c < 2; ++c)
            async_load16(Kg + (size_t)kt * 4096 + (size_t)(c * 256 + tid) * 8,
                         &Ks[(c * 256 + wave * 64) * 8]);
        #pragma unroll
        for (int c = 0; c < 2; ++c) {
            const int e = (c * 256 + tid) * 8;
            async_load16(Vg + (size_t)(e >> 6) * T + kt * 64 + (e & 63),
                         &Vts[(c * 256 + wave * 64) * 8]);
        }
        __syncthreads();                // tiles resident

        const int k0 = kt * 64;
        if (k0 > qbw + 31) continue;    // whole wave masked (both barriers already hit)
        const bool tail = (k0 + 63 > qbw);

        // ---- S^T = K·Q^T ----
        floatx4 sacc[4][2] = {};
        #pragma unroll
        for (int nj = 0; nj < 4; ++nj) {
            if (tail && k0 + nj * 16 > qbw + 31) continue;  // fully masked for both qj
            short8 ak[2];
            #pragma unroll
            for (int ks = 0; ks < 2; ++ks) {
                const int row = nj * 16 + ln;
                const int ch = (ks * 4 + quad) ^ (row & 7);
                ak[ks] = *(const short8*)&Ks[row * 64 + ch * 8];
            }
            #pragma unroll
            for (int qj = 0; qj < 2; ++qj) {
                if (tail && k0 + nj * 16 > qbw + qj * 16 + 15) continue;
                #pragma unroll
                for (int ks = 0; ks < 2; ++ks)
                    sacc[nj][qj] = __builtin_amdgcn_mfma_f32_16x16x32_bf16(
                        ak[ks], bq[qj][ks], sacc[nj][qj], 0, 0, 0);
            }
        }

        if (tail) {  // causal mask; also forces skipped (zero) frags to -inf
            #pragma unroll
            for (int nj = 0; nj < 4; ++nj)
                #pragma unroll
                for (int qj = 0; qj < 2; ++qj) {
                    const int qq = qbw + qj * 16 + ln;
                    #pragma unroll
                    for (int r = 0; r < 4; ++r) {
                        const int kk = k0 + nj * 16 + quad * 4 + r;
                        if (kk > qq) sacc[nj][qj][r] = -1e30f;
                    }
                }
        }

        // ---- online softmax (log2 domain; scale folded into Q) ----
        #pragma unroll
        for (int qj = 0; qj < 2; ++qj) {
            float mx = sacc[0][qj][0];
            #pragma unroll
            for (int nj = 0; nj < 4; ++nj)
                #pragma unroll
                for (int r = 0; r < 4; ++r) mx = fmaxf(mx, sacc[nj][qj][r]);
            mx = fmaxf(mx, __shfl_xor(mx, 16, 64));
            mx = fmaxf(mx, __shfl_xor(mx, 32, 64));
            const float mn = fmaxf(rm[qj], mx);
            const float alpha = exp2f(rm[qj] - mn);
            rm[qj] = mn;
            rl[qj] *= alpha;
            #pragma unroll
            for (int dt = 0; dt < 4; ++dt) oacc[dt][qj] *= alpha;
            float rs = 0.f;
            const int qrow = wave * 32 + qj * 16 + ln;
            #pragma unroll
            for (int nj = 0; nj < 4; ++nj) {
                float p[4];
                #pragma unroll
                for (int r = 0; r < 4; ++r) {
                    p[r] = exp2f(sacc[nj][qj][r] - mn);
                    rs += p[r];
                }
                const int kcol = nj * 16 + quad * 4;
                const int ch = (kcol >> 3) ^ (qrow & 7);
                uint2 w2 = { pack2(p[0], p[1]), pack2(p[2], p[3]) };
                *(uint2*)&Ps[qrow * 64 + ch * 8 + (kcol & 7)] = w2;  // b64, conflict-free
            }
            rl[qj] += rs;
        }

        // ---- O^T += V^T·P^T (wave reads only its own P rows: no barrier) ----
        #pragma unroll
        for (int ks4 = 0; ks4 < 2; ++ks4) {
            short8 bp[2];
            #pragma unroll
            for (int qj = 0; qj < 2; ++qj) {
                const int qrow = wave * 32 + qj * 16 + ln;
                const int ch = (ks4 * 4 + quad) ^ (qrow & 7);
                bp[qj] = *(const short8*)&Ps[qrow * 64 + ch * 8];
            }
            #pragma unroll
            for (int dt = 0; dt < 4; ++dt) {
                const int row = dt * 16 + ln;
                const int ch = (ks4 * 4 + quad) ^ (row & 7);
                const short8 av = *(const short8*)&Vts[row * 64 + ch * 8];
                #pragma unroll
                for (int qj = 0; qj < 2; ++qj)
                    oacc[dt][qj] = __builtin_amdgcn_mfma_f32_16x16x32_bf16(
                        av, bp[qj], oacc[dt][qj], 0, 0, 0);
            }
        }
    }

    // epilogue: normalize, write O[b][t][h*64+d] bf16 (packed b64)
    const int b = bh >> 4, h = bh & 15;
    #pragma unroll
    for (int qj = 0; qj < 2; ++qj) {
        float l = rl[qj];
        l += __shfl_xor(l, 16, 64);
        l += __shfl_xor(l, 32, 64);
        const float inv = 1.0f / l;
        const int t = q0 + wave * 32 + qj * 16 + ln;
        const size_t rowb = ((size_t)b * 1024 + t) * 1024 + h * 64;
        #pragma unroll
        for (int dt = 0; dt < 4; ++dt) {
            uint2 w2 = { pack2(oacc[dt][qj][0] * inv, oacc[dt][qj][1] * inv),
                         pack2(oacc[dt][qj][2] * inv, oacc[dt][qj][3] * inv) };
            *(uint2*)&O[rowb + dt * 16 + quad * 4] = w2;
        }
    }
}

extern "C" void kernel_launch(void* const* d_in, const int* in_sizes, int n_in,
                              void* d_out, int out_size, void* d_ws, size_t ws_size,
                              hipStream_t stream) {
    const float* x     = (const float*)d_in[0];   // [8,1024,1024]
    const float* W_qkv = (const float*)d_in[1];   // [1024,3072]
    const float* b_qkv = (const float*)d_in[2];   // [3072]
    const float* W_out = (const float*)d_in[3];   // [1024,1024]
    const float* b_out = (const float*)d_in[4];   // [1024]
    float* out = (float*)d_out;                   // [8,1024,1024] fp32

    char* ws = (char*)d_ws;
    const size_t MB = 1u << 20;
    bf16* x_bf   = (bf16*)(ws + 0);        // 16 MB  [8192,1024]
    bf16* wqkv_t = (bf16*)(ws + 16 * MB);  //  6 MB  [3072,1024]
    bf16* wout_t = (bf16*)(ws + 22 * MB);  //  2 MB  [1024,1024]
    bf16* q_ws   = (bf16*)(ws + 24 * MB);  // 16 MB  [B,H,T,D] swizzled
    bf16* k_ws   = (bf16*)(ws + 40 * MB);  // 16 MB  [B,H,T,D] swizzled
    bf16* vt_ws  = (bf16*)(ws + 56 * MB);  // 16 MB  [B,H,D,T] swizzled
    bf16* ao_ws  = (bf16*)(ws + 72 * MB);  // 16 MB  [8192,1024]

    cvt_bf16_kernel<<<8192, 256, 0, stream>>>(x, x_bf);
    transpose_cvt_kernel<<<dim3(96, 32), 256, 0, stream>>>(W_qkv, wqkv_t, 1024, 3072);
    transpose_cvt_kernel<<<dim3(32, 32), 256, 0, stream>>>(W_out, wout_t, 1024, 1024);

    gemm_bt_kernel<0><<<dim3(24, 64), 256, 0, stream>>>(
        x_bf, wqkv_t, b_qkv, 1024, q_ws, k_ws, vt_ws, nullptr, 3072);

    attn_kernel<<<dim3(8, 128), 256, 0, stream>>>(q_ws, k_ws, vt_ws, ao_ws);

    gemm_bt_kernel<1><<<dim3(8, 64), 256, 0, stream>>>(
        ao_ws, wout_t, b_out, 1024, nullptr, nullptr, nullptr, out, 1024);
}

// Round 3
// 252.177 us; speedup vs baseline: 1.5183x; 1.1349x over previous
//
#include <hip/hip_runtime.h>
#include <hip/hip_bf16.h>
#include <cstdint>

using bf16 = __hip_bfloat16;
typedef short short8 __attribute__((ext_vector_type(8)));   // 8 bf16 = 4 VGPRs (MFMA A/B frag)
typedef float floatx4 __attribute__((ext_vector_type(4)));  // MFMA C/D frag

// async global->LDS, 16B/lane. LDS dest must be wave-uniform base; HW adds lane*16.
__device__ __forceinline__ void async_load16(const bf16* g, bf16* l) {
    __builtin_amdgcn_global_load_lds(
        (const __attribute__((address_space(1))) uint32_t*)g,
        (__attribute__((address_space(3))) uint32_t*)l, 16, 0, 0);
}

__device__ __forceinline__ uint32_t pack2(float a, float b) {
    union { bf16 h[2]; uint32_t u; } p;
    p.h[0] = __float2bfloat16(a);
    p.h[1] = __float2bfloat16(b);
    return p.u;
}

// ---------------- fp32 -> bf16 bulk convert (x) ----------------
__global__ __launch_bounds__(256)
void cvt_bf16_kernel(const float* __restrict__ in, bf16* __restrict__ out) {
    const int i = (blockIdx.x * 256 + threadIdx.x) * 4;
    const float4 v = *(const float4*)(in + i);
    bf16 o[4] = {__float2bfloat16(v.x), __float2bfloat16(v.y),
                 __float2bfloat16(v.z), __float2bfloat16(v.w)};
    *(ushort4*)(out + i) = *(ushort4*)o;  // 8B store
}

// ------------- fp32 [R][C] -> bf16 [C][R] tiled transpose -------------
__global__ __launch_bounds__(256)
void transpose_cvt_kernel(const float* __restrict__ in, bf16* __restrict__ out,
                          int R, int C) {
    __shared__ float tile[32][33];
    const int tx = threadIdx.x & 31, ty = threadIdx.x >> 5;
    const int c0 = blockIdx.x * 32, r0 = blockIdx.y * 32;
    #pragma unroll
    for (int i = 0; i < 32; i += 8)
        tile[ty + i][tx] = in[(size_t)(r0 + ty + i) * C + c0 + tx];
    __syncthreads();
    #pragma unroll
    for (int i = 0; i < 32; i += 8)
        out[(size_t)(c0 + ty + i) * R + r0 + tx] = __float2bfloat16(tile[tx][ty + i]);
}

// ---------------- m97-pattern GEMM: C = A[M,K] @ Bt[N,K]^T + bias ----------------
// MODE 0: N=3072 qkv epilogue -> scatter Q(scaled, *log2e/8)/K to swizzled [B,H,T,D],
//         V to swizzled [B,H,D,T] bf16. Swizzle: 16B chunks XOR'd by row so that the
//         attention kernel's LDS-resident tiles give conflict-free ds_read_b128.
// MODE 1: N=1024 out epilogue -> fp32 d_out
template <int MODE>
__global__ __launch_bounds__(256, 2)
void gemm_bt_kernel(const bf16* __restrict__ A, const bf16* __restrict__ Bt,
                    const float* __restrict__ bias, int K,
                    bf16* __restrict__ q_ws, bf16* __restrict__ k_ws,
                    bf16* __restrict__ vt_ws, float* __restrict__ out, int N) {
    __shared__ bf16 As[128 * 32];
    __shared__ bf16 Bs[128 * 32];
    const int tid = threadIdx.x;
    const int wave = tid >> 6, lane = tid & 63;
    const int ln = lane & 15, quad = lane >> 4;
    const int wm = wave & 1, wn = wave >> 1;           // 2x2 waves of 64x64
    const int m0 = blockIdx.y * 128, n0 = blockIdx.x * 128;

    floatx4 acc[4][4] = {};

    for (int k0 = 0; k0 < K; k0 += 32) {
        __syncthreads();  // all frag reads of previous tile done
        #pragma unroll
        for (int c = 0; c < 2; ++c) {
            const int e = (c * 256 + tid) * 8;          // linear elem in 128x32 tile
            async_load16(A + (size_t)(m0 + (e >> 5)) * K + k0 + (e & 31),
                         &As[(c * 256 + wave * 64) * 8]);
        }
        #pragma unroll
        for (int c = 0; c < 2; ++c) {
            const int e = (c * 256 + tid) * 8;
            async_load16(Bt + (size_t)(n0 + (e >> 5)) * K + k0 + (e & 31),
                         &Bs[(c * 256 + wave * 64) * 8]);
        }
        __syncthreads();  // drains vmcnt: tiles resident

        short8 af[4], bfr[4];
        #pragma unroll
        for (int i = 0; i < 4; ++i) {
            af[i]  = *(const short8*)&As[(wm * 64 + i * 16 + ln) * 32 + quad * 8];
            bfr[i] = *(const short8*)&Bs[(wn * 64 + i * 16 + ln) * 32 + quad * 8];
        }
        #pragma unroll
        for (int mi = 0; mi < 4; ++mi)
            #pragma unroll
            for (int ni = 0; ni < 4; ++ni)
                acc[mi][ni] = __builtin_amdgcn_mfma_f32_16x16x32_bf16(
                    af[mi], bfr[ni], acc[mi][ni], 0, 0, 0);
    }

    // epilogue; C/D layout: col=lane&15, row=quad*4+reg
    #pragma unroll
    for (int ni = 0; ni < 4; ++ni) {
        const int col = n0 + wn * 64 + ni * 16 + ln;
        const float bv = bias[col];
        if (MODE == 0) {
            const int which = col >> 10;        // 0=q 1=k 2=v (block-uniform)
            const int cc = col & 1023;
            const int h = cc >> 6, d = cc & 63;
            #pragma unroll
            for (int mi = 0; mi < 4; ++mi) {
                const int rowb = m0 + wm * 64 + mi * 16 + quad * 4;
                if (which == 2) {
                    // V^T, packed 4 consecutive t (same swizzle chunk since t%8 in {0,4})
                    const int bb = rowb >> 10, t = rowb & 1023;
                    const int tl = t & 63;
                    const int tt = (t & ~63) + ((((tl >> 3) ^ (d & 7)) << 3) | (tl & 7));
                    uint2 w2 = { pack2(acc[mi][ni][0] + bv, acc[mi][ni][1] + bv),
                                 pack2(acc[mi][ni][2] + bv, acc[mi][ni][3] + bv) };
                    *(uint2*)&vt_ws[((size_t)(bb * 16 + h) * 64 + d) * 1024 + tt] = w2;
                } else {
                    bf16* dst = (which == 0) ? q_ws : k_ws;
                    #pragma unroll
                    for (int r = 0; r < 4; ++r) {
                        const int row = rowb + r;
                        const int bb = row >> 10, t = row & 1023;
                        float v = acc[mi][ni][r] + bv;
                        if (which == 0) v *= 0.1803368801111601f;  // (1/8)*log2(e)
                        const int dd = (((d >> 3) ^ (t & 7)) << 3) | (d & 7);
                        dst[((size_t)(bb * 16 + h) * 1024 + t) * 64 + dd] =
                            __float2bfloat16(v);
                    }
                }
            }
        } else {
            #pragma unroll
            for (int mi = 0; mi < 4; ++mi) {
                const int rowb = m0 + wm * 64 + mi * 16 + quad * 4;
                #pragma unroll
                for (int r = 0; r < 4; ++r)
                    out[(size_t)(rowb + r) * N + col] = acc[mi][ni][r] + bv;
            }
        }
    }
}

// ---------------- causal flash attention (S^T, paired q-tiles, K/V dbuf) ----------------
// grid: x = 4 (pair jt, 7-jt -> uniform 18 k-iters/block), y = b*16+h (128).
// S^T = K·Q^T: C col = q = lane&15 -> softmax reduce = 2 shfl_xor; lane owns P rows
// -> packed b64 P writes. O^T = V^T·P^T keeps all frag reads contiguous b128.
// XOR-swizzle (chunk' = chunk ^ (row&7)) everywhere; global q/k/vt pre-swizzled.
// Q-stage and P share one LDS buffer (Q frags hoisted to regs); K/V double-buffered
// with one barrier per iter: prefetch kt+1 issued before compute on kt.
__global__ __launch_bounds__(256, 3)
void attn_kernel(const bf16* __restrict__ Q, const bf16* __restrict__ K,
                 const bf16* __restrict__ Vt, bf16* __restrict__ O) {
    constexpr int T = 1024;
    __shared__ bf16 QPs[128 * 64];     // Q stage, then P   16 KB
    __shared__ bf16 Ks[2][64 * 64];    // K dbuf            16 KB
    __shared__ bf16 Vts[2][64 * 64];   // V^T dbuf          16 KB

    const int bh = blockIdx.y;
    const int tid = threadIdx.x;
    const int wave = tid >> 6, lane = tid & 63;
    const int ln = lane & 15, quad = lane >> 4;

    const bf16* Kg = K + (size_t)bh * T * 64;
    const bf16* Vg = Vt + (size_t)bh * 64 * T;
    const int b = bh >> 4, h = bh & 15;

    #pragma unroll
    for (int phase = 0; phase < 2; ++phase) {
        const int jt = phase ? 7 - blockIdx.x : blockIdx.x;
        const int q0 = jt * 128;
        const int nkt = 2 * jt + 2;

        // stage Q (128x64) into QPs and K/V tile 0 into buf 0
        const bf16* Qg = Q + (size_t)bh * T * 64 + (size_t)q0 * 64;
        #pragma unroll
        for (int c = 0; c < 4; ++c)
            async_load16(Qg + (size_t)(c * 256 + tid) * 8,
                         &QPs[(c * 256 + wave * 64) * 8]);
        #pragma unroll
        for (int c = 0; c < 2; ++c)
            async_load16(Kg + (size_t)(c * 256 + tid) * 8,
                         &Ks[0][(c * 256 + wave * 64) * 8]);
        #pragma unroll
        for (int c = 0; c < 2; ++c) {
            const int e = (c * 256 + tid) * 8;
            async_load16(Vg + (size_t)(e >> 6) * T + (e & 63),
                         &Vts[0][(c * 256 + wave * 64) * 8]);
        }
        __syncthreads();  // Q + tile0 resident

        // hoist Q B-frags for the whole k-loop: B[d][q], q = lane&15 (QPs then free)
        short8 bq[2][2];
        #pragma unroll
        for (int qj = 0; qj < 2; ++qj)
            #pragma unroll
            for (int ks = 0; ks < 2; ++ks) {
                const int row = wave * 32 + qj * 16 + ln;
                const int ch = (ks * 4 + quad) ^ (row & 7);
                bq[qj][ks] = *(const short8*)&QPs[row * 64 + ch * 8];
            }

        floatx4 oacc[4][2] = {};            // O^T frags [dt][qj]
        float rm[2] = {-1e30f, -1e30f}, rl[2] = {0.f, 0.f};
        const int qbw = q0 + wave * 32;     // wave's lowest q

        for (int kt = 0; kt < nkt; ++kt) {
            const int cur = kt & 1;
            if (kt + 1 < nkt) {             // prefetch next K/V tile into other buf
                const int nxt = cur ^ 1;
                #pragma unroll
                for (int c = 0; c < 2; ++c)
                    async_load16(Kg + (size_t)(kt + 1) * 4096 + (size_t)(c * 256 + tid) * 8,
                                 &Ks[nxt][(c * 256 + wave * 64) * 8]);
                #pragma unroll
                for (int c = 0; c < 2; ++c) {
                    const int e = (c * 256 + tid) * 8;
                    async_load16(Vg + (size_t)(e >> 6) * T + (kt + 1) * 64 + (e & 63),
                                 &Vts[nxt][(c * 256 + wave * 64) * 8]);
                }
            }

            const int k0 = kt * 64;
            if (k0 <= qbw + 31) {           // else: whole wave masked, just barrier
                const bool tail = (k0 + 63 > qbw);

                // ---- S^T = K·Q^T ----
                floatx4 sacc[4][2] = {};
                #pragma unroll
                for (int nj = 0; nj < 4; ++nj) {
                    if (tail && k0 + nj * 16 > qbw + 31) continue;
                    short8 ak[2];
                    #pragma unroll
                    for (int ks = 0; ks < 2; ++ks) {
                        const int row = nj * 16 + ln;
                        const int ch = (ks * 4 + quad) ^ (row & 7);
                        ak[ks] = *(const short8*)&Ks[cur][row * 64 + ch * 8];
                    }
                    #pragma unroll
                    for (int qj = 0; qj < 2; ++qj) {
                        if (tail && k0 + nj * 16 > qbw + qj * 16 + 15) continue;
                        #pragma unroll
                        for (int ks = 0; ks < 2; ++ks)
                            sacc[nj][qj] = __builtin_amdgcn_mfma_f32_16x16x32_bf16(
                                ak[ks], bq[qj][ks], sacc[nj][qj], 0, 0, 0);
                    }
                }

                if (tail) {  // causal mask; also forces skipped (zero) frags to -inf
                    #pragma unroll
                    for (int nj = 0; nj < 4; ++nj)
                        #pragma unroll
                        for (int qj = 0; qj < 2; ++qj) {
                            const int qq = qbw + qj * 16 + ln;
                            #pragma unroll
                            for (int r = 0; r < 4; ++r) {
                                const int kk = k0 + nj * 16 + quad * 4 + r;
                                if (kk > qq) sacc[nj][qj][r] = -1e30f;
                            }
                        }
                }

                // ---- online softmax (log2 domain; scale folded into Q) ----
                #pragma unroll
                for (int qj = 0; qj < 2; ++qj) {
                    float mx = sacc[0][qj][0];
                    #pragma unroll
                    for (int nj = 0; nj < 4; ++nj)
                        #pragma unroll
                        for (int r = 0; r < 4; ++r) mx = fmaxf(mx, sacc[nj][qj][r]);
                    mx = fmaxf(mx, __shfl_xor(mx, 16, 64));
                    mx = fmaxf(mx, __shfl_xor(mx, 32, 64));
                    const float mn = fmaxf(rm[qj], mx);
                    const float alpha = exp2f(rm[qj] - mn);
                    rm[qj] = mn;
                    rl[qj] *= alpha;
                    #pragma unroll
                    for (int dt = 0; dt < 4; ++dt) oacc[dt][qj] *= alpha;
                    float rs = 0.f;
                    const int qrow = wave * 32 + qj * 16 + ln;
                    #pragma unroll
                    for (int nj = 0; nj < 4; ++nj) {
                        float p[4];
                        #pragma unroll
                        for (int r = 0; r < 4; ++r) {
                            p[r] = exp2f(sacc[nj][qj][r] - mn);
                            rs += p[r];
                        }
                        const int kcol = nj * 16 + quad * 4;
                        const int ch = (kcol >> 3) ^ (qrow & 7);
                        uint2 w2 = { pack2(p[0], p[1]), pack2(p[2], p[3]) };
                        *(uint2*)&QPs[qrow * 64 + ch * 8 + (kcol & 7)] = w2;
                    }
                    rl[qj] += rs;
                }

                // ---- O^T += V^T·P^T (wave reads only its own P rows: no barrier) ----
                #pragma unroll
                for (int ks4 = 0; ks4 < 2; ++ks4) {
                    short8 bp[2];
                    #pragma unroll
                    for (int qj = 0; qj < 2; ++qj) {
                        const int qrow = wave * 32 + qj * 16 + ln;
                        const int ch = (ks4 * 4 + quad) ^ (qrow & 7);
                        bp[qj] = *(const short8*)&QPs[qrow * 64 + ch * 8];
                    }
                    #pragma unroll
                    for (int dt = 0; dt < 4; ++dt) {
                        const int row = dt * 16 + ln;
                        const int ch = (ks4 * 4 + quad) ^ (row & 7);
                        const short8 av = *(const short8*)&Vts[cur][row * 64 + ch * 8];
                        #pragma unroll
                        for (int qj = 0; qj < 2; ++qj)
                            oacc[dt][qj] = __builtin_amdgcn_mfma_f32_16x16x32_bf16(
                                av, bp[qj], oacc[dt][qj], 0, 0, 0);
                    }
                }
            }

            __syncthreads();  // readers of cur done; prefetch (into nxt) drained
        }

        // epilogue: normalize, write O[b][t][h*64+d] bf16 (packed b64)
        #pragma unroll
        for (int qj = 0; qj < 2; ++qj) {
            float l = rl[qj];
            l += __shfl_xor(l, 16, 64);
            l += __shfl_xor(l, 32, 64);
            const float inv = 1.0f / l;
            const int t = q0 + wave * 32 + qj * 16 + ln;
            const size_t rowb = ((size_t)b * 1024 + t) * 1024 + h * 64;
            #pragma unroll
            for (int dt = 0; dt < 4; ++dt) {
                uint2 w2 = { pack2(oacc[dt][qj][0] * inv, oacc[dt][qj][1] * inv),
                             pack2(oacc[dt][qj][2] * inv, oacc[dt][qj][3] * inv) };
                *(uint2*)&O[rowb + dt * 16 + quad * 4] = w2;
            }
        }
    }
}

extern "C" void kernel_launch(void* const* d_in, const int* in_sizes, int n_in,
                              void* d_out, int out_size, void* d_ws, size_t ws_size,
                              hipStream_t stream) {
    const float* x     = (const float*)d_in[0];   // [8,1024,1024]
    const float* W_qkv = (const float*)d_in[1];   // [1024,3072]
    const float* b_qkv = (const float*)d_in[2];   // [3072]
    const float* W_out = (const float*)d_in[3];   // [1024,1024]
    const float* b_out = (const float*)d_in[4];   // [1024]
    float* out = (float*)d_out;                   // [8,1024,1024] fp32

    char* ws = (char*)d_ws;
    const size_t MB = 1u << 20;
    bf16* x_bf   = (bf16*)(ws + 0);        // 16 MB  [8192,1024]
    bf16* wqkv_t = (bf16*)(ws + 16 * MB);  //  6 MB  [3072,1024]
    bf16* wout_t = (bf16*)(ws + 22 * MB);  //  2 MB  [1024,1024]
    bf16* q_ws   = (bf16*)(ws + 24 * MB);  // 16 MB  [B,H,T,D] swizzled
    bf16* k_ws   = (bf16*)(ws + 40 * MB);  // 16 MB  [B,H,T,D] swizzled
    bf16* vt_ws  = (bf16*)(ws + 56 * MB);  // 16 MB  [B,H,D,T] swizzled
    bf16* ao_ws  = (bf16*)(ws + 72 * MB);  // 16 MB  [8192,1024]

    cvt_bf16_kernel<<<8192, 256, 0, stream>>>(x, x_bf);
    transpose_cvt_kernel<<<dim3(96, 32), 256, 0, stream>>>(W_qkv, wqkv_t, 1024, 3072);
    transpose_cvt_kernel<<<dim3(32, 32), 256, 0, stream>>>(W_out, wout_t, 1024, 1024);

    gemm_bt_kernel<0><<<dim3(24, 64), 256, 0, stream>>>(
        x_bf, wqkv_t, b_qkv, 1024, q_ws, k_ws, vt_ws, nullptr, 3072);

    attn_kernel<<<dim3(4, 128), 256, 0, stream>>>(q_ws, k_ws, vt_ws, ao_ws);

    gemm_bt_kernel<1><<<dim3(8, 64), 256, 0, stream>>>(
        ao_ws, wout_t, b_out, 1024, nullptr, nullptr, nullptr, out, 1024);
}